// Round 14
// baseline (138.226 us; speedup 1.0000x reference)
//
#include <hip/hip_runtime.h>
#include <hip/hip_bf16.h>

#define NREPS   16
#define NELEMS  128
#define DD      32
#define MATSZ   (DD * DD)        // 1024 elements per 32x32 block
#define EMB     (NREPS * MATSZ)  // 16384

typedef __attribute__((ext_vector_type(8))) short bf16x8;  // 8 bf16 = 4 VGPR
typedef __attribute__((ext_vector_type(4))) float f32x4;   // MFMA C/D frag

static __device__ __forceinline__ short f2bf(float f) {
    __hip_bfloat16 h = __float2bfloat16(f);   // RTN
    return *reinterpret_cast<short*>(&h);
}

// Streaming store: nt (LRU-first) + sc1 (write-through past L2/L3 -- no cache
// allocation). The C++ nontemporal builtin only emits nt, which is a HINT:
// R7/R8 measured FETCH=139-144MB, i.e. the 256MB out stream still evicted
// ~45% of emb from the Infinity Cache every replay. sc1 makes the bypass
// structural; emb (exactly 256MiB = L3 size) can then stay L3-resident
// across graph replays.
static __device__ __forceinline__ void store_stream(float* p, float v) {
    asm volatile("global_store_dword %0, %1, off nt sc1"
                 :: "v"(p), "v"(v) : "memory");
}

// ---- Prep: Mt[mat][col][k] = bf16( reps[mat][k][col] / (||.||_F + 1e-6) ) ----
// One block per (r,e) matrix. Coalesced 4KB read, padded-LDS transpose,
// coalesced 2KB bf16 write. Norm + transpose leave the hot path entirely;
// the 4MB bf16 table fits a per-XCD L2.
__global__ __launch_bounds__(256) void prep_kernel(
    const float* __restrict__ reps, ushort* __restrict__ Mt)
{
    __shared__ float lM[DD * 33];          // +1 pad: transpose reads 2-way max
    __shared__ float red[4];
    const int mat = blockIdx.x;            // r*128 + e
    const int t   = threadIdx.x;           // 0..255

    float4 v = reinterpret_cast<const float4*>(reps + (size_t)mat * MATSZ)[t];
    const int i  = t >> 3;                 // row
    const int c0 = (t & 7) << 2;           // col base
    lM[i * 33 + c0 + 0] = v.x;
    lM[i * 33 + c0 + 1] = v.y;
    lM[i * 33 + c0 + 2] = v.z;
    lM[i * 33 + c0 + 3] = v.w;

    float s = v.x * v.x + v.y * v.y + v.z * v.z + v.w * v.w;
    #pragma unroll
    for (int off = 32; off; off >>= 1) s += __shfl_xor(s, off, 64);
    if ((t & 63) == 0) red[t >> 6] = s;
    __syncthreads();
    const float scale = 1.0f / (sqrtf(red[0] + red[1] + red[2] + red[3]) + 1e-6f);

    // thread t writes transposed elements q = t*4..t*4+3 (q = col*32 + k)
    const int col = t >> 3;
    const int k0  = (t & 7) << 2;
    ushort4 o;
    o.x = (ushort)f2bf(lM[(k0 + 0) * 33 + col] * scale);
    o.y = (ushort)f2bf(lM[(k0 + 1) * 33 + col] * scale);
    o.z = (ushort)f2bf(lM[(k0 + 2) * 33 + col] * scale);
    o.w = (ushort)f2bf(lM[(k0 + 3) * 33 + col] * scale);
    reinterpret_cast<ushort4*>(Mt + (size_t)mat * MATSZ)[t] = o;
}

// ---- Main: EXACTLY the proven R8 shape (best so far, 104.7us): one wave =
// two (b,r) blocks, 12 loads, 4+4 MFMAs, scalar streaming stores. The ONLY
// change vs R8 is the store cache policy (nt -> nt+sc1), a one-variable
// experiment on write-stream L3 bypass.
// A-frag: lane holds A[ti*16+(l&15)][(l>>4)*8..+7] -> two dwordx4 from global.
// B-frag: lane holds Mn[k0..k0+7][tj*16+(l&15)] -> one dwordx4 from Mt
//   (bf16 normalized transposed table, L2-resident, fully line-coalesced).
// C-frag (m89-verified): row=(l>>4)*4+m, col=l&15.
__global__ __launch_bounds__(256) void trans_mfma2_kernel(
    const float*  __restrict__ emb,    // [B][16384] fp32
    const int*    __restrict__ syms,   // [B]
    const ushort* __restrict__ Mt,     // [2048][32][32] bf16 (normalized, T)
    const int*    __restrict__ trans,  // [64]
    float*        __restrict__ out)    // [B][16384]
{
    const int bid = blockIdx.x;            // 0 .. B*2-1
    const int b   = bid >> 1;
    const int w   = threadIdx.x >> 6;      // wave 0..3
    const int l   = threadIdx.x & 63;
    const int rr  = ((bid & 1) << 3) | (w << 1);   // first rep of the pair

    const int esym = trans[syms[b]];
    const int lr = l & 15;                 // row (A) / col (B,C) within tile
    const int k0 = (l >> 4) << 3;          // k base {0,8,16,24}

    const float*  A0 = emb + (size_t)b * EMB + (size_t)rr * MATSZ;
    const ushort* M0 = Mt + ((size_t)rr * NELEMS + esym) * MATSZ;

    // ---- issue the pair's loads (12 independent VMEM instructions) ----
    float4 alo[2][2], ahi[2][2];
    bf16x8 bfg[2][2];
    #pragma unroll
    for (int p = 0; p < 2; ++p) {
        const float*  A = A0 + p * MATSZ;
        const ushort* M = M0 + (size_t)p * NELEMS * MATSZ;
        #pragma unroll
        for (int ti = 0; ti < 2; ++ti) {
            const float* ap = A + (ti * 16 + lr) * DD + k0;
            alo[p][ti] = *reinterpret_cast<const float4*>(ap);
            ahi[p][ti] = *reinterpret_cast<const float4*>(ap + 4);
        }
        #pragma unroll
        for (int tj = 0; tj < 2; ++tj)
            bfg[p][tj] = *reinterpret_cast<const bf16x8*>(M + (tj * 16 + lr) * DD + k0);
    }

    const f32x4 z = {0.0f, 0.0f, 0.0f, 0.0f};
    const int row0 = (l >> 4) << 2;        // C row base

    #pragma unroll
    for (int p = 0; p < 2; ++p) {
        bf16x8 af[2];
        #pragma unroll
        for (int ti = 0; ti < 2; ++ti) {
            bf16x8 f;
            f[0] = f2bf(alo[p][ti].x); f[1] = f2bf(alo[p][ti].y);
            f[2] = f2bf(alo[p][ti].z); f[3] = f2bf(alo[p][ti].w);
            f[4] = f2bf(ahi[p][ti].x); f[5] = f2bf(ahi[p][ti].y);
            f[6] = f2bf(ahi[p][ti].z); f[7] = f2bf(ahi[p][ti].w);
            af[ti] = f;
        }

        f32x4 acc[2][2];
        #pragma unroll
        for (int ti = 0; ti < 2; ++ti)
            #pragma unroll
            for (int tj = 0; tj < 2; ++tj)
                acc[ti][tj] = __builtin_amdgcn_mfma_f32_16x16x32_bf16(
                    af[ti], bfg[p][tj], z, 0, 0, 0);

        float* Ob = out + (size_t)b * EMB + (size_t)(rr + p) * MATSZ;
        #pragma unroll
        for (int ti = 0; ti < 2; ++ti)
            #pragma unroll
            for (int m = 0; m < 4; ++m) {
                const int row = ti * 16 + row0 + m;
                #pragma unroll
                for (int tj = 0; tj < 2; ++tj)
                    store_stream(Ob + row * DD + tj * 16 + lr,
                                 acc[ti][tj][m]);
            }
    }
}

extern "C" void kernel_launch(void* const* d_in, const int* in_sizes, int n_in,
                              void* d_out, int out_size, void* d_ws, size_t ws_size,
                              hipStream_t stream) {
    const float* emb   = (const float*)d_in[0];
    const int*   syms  = (const int*)d_in[1];
    const float* reps  = (const float*)d_in[2];
    const int*   trans = (const int*)d_in[3];
    float*  outp = (float*)d_out;
    ushort* Mt   = (ushort*)d_ws;          // 2048 * 2KB = 4 MB scratch

    const int B = in_sizes[1];             // batch count (4096)

    hipLaunchKernelGGL(prep_kernel, dim3(NREPS * NELEMS), dim3(256), 0, stream,
                       reps, Mt);
    hipLaunchKernelGGL(trans_mfma2_kernel, dim3(B * 2), dim3(256), 0, stream,
                       emb, syms, Mt, trans, outp);
}

// Round 15
// 101.948 us; speedup vs baseline: 1.3558x; 1.3558x over previous
//
#include <hip/hip_runtime.h>
#include <hip/hip_bf16.h>

#define NREPS   16
#define NELEMS  128
#define DD      32
#define MATSZ   (DD * DD)        // 1024 elements per 32x32 block
#define EMB     (NREPS * MATSZ)  // 16384

typedef __attribute__((ext_vector_type(8))) short bf16x8;  // 8 bf16 = 4 VGPR
typedef __attribute__((ext_vector_type(4))) float f32x4;   // MFMA C/D frag

static __device__ __forceinline__ short f2bf(float f) {
    __hip_bfloat16 h = __float2bfloat16(f);   // RTN
    return *reinterpret_cast<short*>(&h);
}

// ---- Prep: Mt[mat][col][k] = bf16( reps[mat][k][col] / (||.||_F + 1e-6) ) ----
// One block per (r,e) matrix. Coalesced 4KB read, padded-LDS transpose,
// coalesced 2KB bf16 write. Norm + transpose leave the hot path entirely;
// the 4MB bf16 table fits a per-XCD L2.
__global__ __launch_bounds__(256) void prep_kernel(
    const float* __restrict__ reps, ushort* __restrict__ Mt)
{
    __shared__ float lM[DD * 33];          // +1 pad: transpose reads 2-way max
    __shared__ float red[4];
    const int mat = blockIdx.x;            // r*128 + e
    const int t   = threadIdx.x;           // 0..255

    float4 v = reinterpret_cast<const float4*>(reps + (size_t)mat * MATSZ)[t];
    const int i  = t >> 3;                 // row
    const int c0 = (t & 7) << 2;           // col base
    lM[i * 33 + c0 + 0] = v.x;
    lM[i * 33 + c0 + 1] = v.y;
    lM[i * 33 + c0 + 2] = v.z;
    lM[i * 33 + c0 + 3] = v.w;

    float s = v.x * v.x + v.y * v.y + v.z * v.z + v.w * v.w;
    #pragma unroll
    for (int off = 32; off; off >>= 1) s += __shfl_xor(s, off, 64);
    if ((t & 63) == 0) red[t >> 6] = s;
    __syncthreads();
    const float scale = 1.0f / (sqrtf(red[0] + red[1] + red[2] + red[3]) + 1e-6f);

    // thread t writes transposed elements q = t*4..t*4+3 (q = col*32 + k)
    const int col = t >> 3;
    const int k0  = (t & 7) << 2;
    ushort4 o;
    o.x = (ushort)f2bf(lM[(k0 + 0) * 33 + col] * scale);
    o.y = (ushort)f2bf(lM[(k0 + 1) * 33 + col] * scale);
    o.z = (ushort)f2bf(lM[(k0 + 2) * 33 + col] * scale);
    o.w = (ushort)f2bf(lM[(k0 + 3) * 33 + col] * scale);
    reinterpret_cast<ushort4*>(Mt + (size_t)mat * MATSZ)[t] = o;
}

// ---- Main: the proven R8 kernel, exact revert (best measured: 104.7us).
// One wave = TWO (b,r) blocks (reps rr, rr+1). 12 VMEM loads, 2x4 MFMAs,
// 32 scalar non-temporal stores.
// A-frag: lane holds A[ti*16+(l&15)][(l>>4)*8..+7] -> two dwordx4 from global.
// B-frag: lane holds Mn[k0..k0+7][tj*16+(l&15)] -> one dwordx4 from Mt
//   (bf16 normalized transposed table, L2-resident, fully line-coalesced).
// C-frag (m89-verified): row=(l>>4)*4+m, col=l&15.
// Stores non-temporal (nt only -- sc1 write-through regressed 33us in R14):
// keeps the 256MB out stream from evicting emb from the Infinity Cache
// (proven: FETCH 144MB < 256MB; scalar-store write-amp 1.04x).
__global__ __launch_bounds__(256) void trans_mfma2_kernel(
    const float*  __restrict__ emb,    // [B][16384] fp32
    const int*    __restrict__ syms,   // [B]
    const ushort* __restrict__ Mt,     // [2048][32][32] bf16 (normalized, T)
    const int*    __restrict__ trans,  // [64]
    float*        __restrict__ out)    // [B][16384]
{
    const int bid = blockIdx.x;            // 0 .. B*2-1
    const int b   = bid >> 1;
    const int w   = threadIdx.x >> 6;      // wave 0..3
    const int l   = threadIdx.x & 63;
    const int rr  = ((bid & 1) << 3) | (w << 1);   // first rep of the pair

    const int esym = trans[syms[b]];
    const int lr = l & 15;                 // row (A) / col (B,C) within tile
    const int k0 = (l >> 4) << 3;          // k base {0,8,16,24}

    const float*  A0 = emb + (size_t)b * EMB + (size_t)rr * MATSZ;
    const ushort* M0 = Mt + ((size_t)rr * NELEMS + esym) * MATSZ;

    // ---- issue the pair's loads (12 independent VMEM instructions) ----
    float4 alo[2][2], ahi[2][2];
    bf16x8 bfg[2][2];
    #pragma unroll
    for (int p = 0; p < 2; ++p) {
        const float*  A = A0 + p * MATSZ;
        const ushort* M = M0 + (size_t)p * NELEMS * MATSZ;
        #pragma unroll
        for (int ti = 0; ti < 2; ++ti) {
            const float* ap = A + (ti * 16 + lr) * DD + k0;
            alo[p][ti] = *reinterpret_cast<const float4*>(ap);
            ahi[p][ti] = *reinterpret_cast<const float4*>(ap + 4);
        }
        #pragma unroll
        for (int tj = 0; tj < 2; ++tj)
            bfg[p][tj] = *reinterpret_cast<const bf16x8*>(M + (tj * 16 + lr) * DD + k0);
    }

    const f32x4 z = {0.0f, 0.0f, 0.0f, 0.0f};
    const int row0 = (l >> 4) << 2;        // C row base

    #pragma unroll
    for (int p = 0; p < 2; ++p) {
        bf16x8 af[2];
        #pragma unroll
        for (int ti = 0; ti < 2; ++ti) {
            bf16x8 f;
            f[0] = f2bf(alo[p][ti].x); f[1] = f2bf(alo[p][ti].y);
            f[2] = f2bf(alo[p][ti].z); f[3] = f2bf(alo[p][ti].w);
            f[4] = f2bf(ahi[p][ti].x); f[5] = f2bf(ahi[p][ti].y);
            f[6] = f2bf(ahi[p][ti].z); f[7] = f2bf(ahi[p][ti].w);
            af[ti] = f;
        }

        f32x4 acc[2][2];
        #pragma unroll
        for (int ti = 0; ti < 2; ++ti)
            #pragma unroll
            for (int tj = 0; tj < 2; ++tj)
                acc[ti][tj] = __builtin_amdgcn_mfma_f32_16x16x32_bf16(
                    af[ti], bfg[p][tj], z, 0, 0, 0);

        float* Ob = out + (size_t)b * EMB + (size_t)(rr + p) * MATSZ;
        #pragma unroll
        for (int ti = 0; ti < 2; ++ti)
            #pragma unroll
            for (int m = 0; m < 4; ++m) {
                const int row = ti * 16 + row0 + m;
                #pragma unroll
                for (int tj = 0; tj < 2; ++tj)
                    __builtin_nontemporal_store(acc[ti][tj][m],
                                                Ob + row * DD + tj * 16 + lr);
            }
    }
}

extern "C" void kernel_launch(void* const* d_in, const int* in_sizes, int n_in,
                              void* d_out, int out_size, void* d_ws, size_t ws_size,
                              hipStream_t stream) {
    const float* emb   = (const float*)d_in[0];
    const int*   syms  = (const int*)d_in[1];
    const float* reps  = (const float*)d_in[2];
    const int*   trans = (const int*)d_in[3];
    float*  outp = (float*)d_out;
    ushort* Mt   = (ushort*)d_ws;          // 2048 * 2KB = 4 MB scratch

    const int B = in_sizes[1];             // batch count (4096)

    hipLaunchKernelGGL(prep_kernel, dim3(NREPS * NELEMS), dim3(256), 0, stream,
                       reps, Mt);
    hipLaunchKernelGGL(trans_mfma2_kernel, dim3(B * 2), dim3(256), 0, stream,
                       emb, syms, Mt, trans, outp);
}